// Round 13
// baseline (1536.537 us; speedup 1.0000x reference)
//
#include <hip/hip_runtime.h>
#include <stdint.h>
#include <string.h>
#include <cmath>

// SpikingYOLO round 13: 16co x 4px conv tile. Numerics BIT-IDENTICAL to R9-R12
// (FMA-sequential f32 conv, k=(ci,kh,kw) ascending, kc=384 flushes at k=384/768,
// bias after, unfused f32 LIF, alpha=0x3F7383C6 beta=0x3F519857).
// R12 post-mortem: 53% of fp32 FMA peak; non-FMA VALU + s_load waits ~30%.
// This round: per (ci,kh) window (3 loads + 9 cvt) serves 192 FMA (was 96);
// weights one s_load_dwordx16 per tap. launch_bounds(256,3) caps VGPR ~170.

#define BB 4
#define TT 10

// padded plane geometry: rows -1..HIN-1 (HIN+1 rows), cols -4..HIN+3 (HIN+8)
// L2 input (s1p):  HIN=128: row stride 136 B, plane 129*136 = 17544 B
// L3 input (s2p):  HIN=64 : row stride 72 B,  plane 65*72   = 4680 B

// ------------------------------------------------ zero the pad borders
template<int RS_DW, int NROWS>
__global__ __launch_bounds__(256) void zpad(uint32_t* __restrict__ buf) {
    const int plane = blockIdx.x;
    const int j = threadIdx.x;
    uint32_t* p = buf + (size_t)plane * (RS_DW * NROWS);
    if (j < NROWS) p[j * RS_DW] = 0u;                    // cols -4..-1 of every row
    const int k = j - NROWS;
    if (k >= 0 && k < RS_DW - 1) p[k + 1] = 0u;          // rest of top pad row (-1)
}

// ---------------------------------------------------------------- conv1+LIF
// unchanged numerics from R9; writes u8 spikes into padded s1p layout.
__global__ __launch_bounds__(256) void conv1_lif(
    const float* __restrict__ x,    // [4,2,128,128,10]
    const float* __restrict__ w1,   // [64,2,3,3]
    const float* __restrict__ b1,   // [64]
    uint8_t* __restrict__ s1p,      // padded [40*64][129][136]
    float alpha, float beta)
{
    __shared__ float xs[2][3][10][10];   // [ci][kh][wi][t]
    __shared__ float wsh[18][64];        // [tap][co]
    const int tid = threadIdx.x;
    const int b = blockIdx.z, h = blockIdx.y, w0 = blockIdx.x * 8;

    for (int i = tid; i < 1152; i += 256) {
        int co = i & 63, tap = i >> 6;
        wsh[tap][co] = w1[co * 18 + tap];
    }
    for (int i = tid; i < 600; i += 256) {
        int t = i % 10; int rest = i / 10;
        int wi = rest % 10; rest /= 10;
        int kh = rest % 3; int ci = rest / 3;
        int hh = h - 1 + kh, ww = w0 - 1 + wi;
        float v = 0.f;
        if (hh >= 0 && hh < 128 && ww >= 0 && ww < 128)
            v = x[(((b * 2 + ci) * 128 + hh) * 128 + ww) * 10 + t];
        xs[ci][kh][wi][t] = v;
    }
    __syncthreads();

    const int px  = tid & 7;
    const int cog = (tid >> 3) * 2;
    float acc[2][10];
#pragma unroll
    for (int c = 0; c < 2; ++c)
#pragma unroll
        for (int t = 0; t < 10; ++t) acc[c][t] = 0.f;

#pragma unroll
    for (int tap = 0; tap < 18; ++tap) {
        const int ci = tap / 9, kh = (tap % 9) / 3, kw = tap % 3;
        float2 wv = *(const float2*)&wsh[tap][cog];
#pragma unroll
        for (int t = 0; t < 10; ++t) {
            float xv = xs[ci][kh][px + kw][t];
            acc[0][t] = __fmaf_rn(wv.x, xv, acc[0][t]);
            acc[1][t] = __fmaf_rn(wv.y, xv, acc[1][t]);
        }
    }
#pragma unroll
    for (int c = 0; c < 2; ++c) {
        const float bv = b1[cog + c];
        float syn = 0.f, mem = 0.f;
#pragma unroll
        for (int t = 0; t < 10; ++t) {
            float cur = __fadd_rn(acc[c][t], bv);
            syn = __fadd_rn(__fmul_rn(beta, syn), cur);
            mem = __fadd_rn(__fmul_rn(alpha, mem), syn);
            float sp = (mem >= 1.0f) ? 1.0f : 0.0f;
            mem = __fsub_rn(mem, sp);
            s1p[(uint32_t)((t * BB + b) * 64 + (cog + c)) * 17544u
                + (h + 1) * 136 + (w0 + px + 4)] = (uint8_t)sp;
        }
    }
}

// --------------------------------------------------- weight transpose kernel
__global__ __launch_bounds__(256) void wtrans(
    const float* __restrict__ w, float* __restrict__ wt, int K, int COUT)
{
    int i = blockIdx.x * 256 + threadIdx.x;
    if (i < K * COUT) {
        int k = i / COUT, co = i - k * COUT;
        wt[i] = w[co * K + k];
    }
}

// ------------------------------------------------- per-ci conv taps (inlined)
// 16co x 4px; padded input -> no masks. sv[c] = spike at in-col 8w4-1+c.
template<int COUT, int PLANE, int KHB, int KHE>
__device__ __forceinline__ void conv_ci16(
    int ci, const uint8_t* __restrict__ fb, const float* __restrict__ wt,
    int cob, const int off[3], float part[64])
{
    const uint8_t* p = fb + (uint32_t)ci * PLANE;
    uint32_t d0[3], d1[3], d2[3];
#pragma unroll
    for (int kh = KHB; kh < KHE; ++kh) {
        const uint8_t* q = p + off[kh];
        uint2 v = *(const uint2*)q;          // 8B-aligned (row stride % 8 == 0)
        d0[kh] = v.x; d1[kh] = v.y;
        d2[kh] = *(const uint32_t*)(q + 8);
    }
#pragma unroll
    for (int kh = KHB; kh < KHE; ++kh) {
        float sv[9];
        sv[0] = (float)(d0[kh] >> 24);
        sv[1] = (float)(d1[kh] & 0xffu);
        sv[2] = (float)((d1[kh] >> 8) & 0xffu);
        sv[3] = (float)((d1[kh] >> 16) & 0xffu);
        sv[4] = (float)(d1[kh] >> 24);
        sv[5] = (float)(d2[kh] & 0xffu);
        sv[6] = (float)((d2[kh] >> 8) & 0xffu);
        sv[7] = (float)((d2[kh] >> 16) & 0xffu);
        sv[8] = (float)(d2[kh] >> 24);
#pragma unroll
        for (int kw = 0; kw < 3; ++kw) {
            const float* wp = wt + (ci * 9 + kh * 3 + kw) * COUT + cob; // uniform -> s_load_dwordx16
#pragma unroll
            for (int co = 0; co < 16; ++co) {
                const float wv = wp[co];
#pragma unroll
                for (int j = 0; j < 4; ++j)
                    part[co * 4 + j] = __fmaf_rn(wv, sv[2 * j + kw], part[co * 4 + j]);
            }
        }
    }
}

// -------------------- stride-2 3x3 conv, t-parallel, currents out (no LIF)
// thread: 16co x 4px; padded u8 input; no LDS/barriers/masks.
template<int CIN, int COUT, int HOUT, int WTH, int PLANE, int RS,
         int F1CI, int F1KH, int F2CI, int F2KH>
__global__ __launch_bounds__(256, 3) void conv_g16(
    const uint8_t* __restrict__ sin,   // padded planes [40*CIN][...]
    const float* __restrict__ wt,      // [CIN*9][COUT] transposed
    float* __restrict__ cur)           // [40,COUT,HOUT,HOUT] pre-bias currents
{
    const int tid = threadIdx.x;
    const int w4  = tid & (WTH - 1);
    const int hh  = blockIdx.x * (256 / WTH) + (tid / WTH);
    const int cob = blockIdx.y * 16;
    const int f   = blockIdx.z;

    const uint8_t* fb = sin + (size_t)f * CIN * PLANE;
    int off[3];
#pragma unroll
    for (int kh = 0; kh < 3; ++kh) off[kh] = (2 * hh + kh) * RS + 8 * w4;

    float part[64], tot[64];
#pragma unroll
    for (int n = 0; n < 64; ++n) { part[n] = 0.f; tot[n] = 0.f; }

    for (int ci = 0; ci < F1CI; ++ci)
        conv_ci16<COUT,PLANE,0,3>(ci, fb, wt, cob, off, part);
    // kc flush #1 at global k=384
    conv_ci16<COUT,PLANE,0,F1KH>(F1CI, fb, wt, cob, off, part);
#pragma unroll
    for (int n = 0; n < 64; ++n) { tot[n] = __fadd_rn(tot[n], part[n]); part[n] = 0.f; }
    conv_ci16<COUT,PLANE,F1KH,3>(F1CI, fb, wt, cob, off, part);
    if constexpr (F2CI < CIN) {
        for (int ci = F1CI + 1; ci < F2CI; ++ci)
            conv_ci16<COUT,PLANE,0,3>(ci, fb, wt, cob, off, part);
        // kc flush #2 at global k=768
        conv_ci16<COUT,PLANE,0,F2KH>(F2CI, fb, wt, cob, off, part);
#pragma unroll
        for (int n = 0; n < 64; ++n) { tot[n] = __fadd_rn(tot[n], part[n]); part[n] = 0.f; }
        conv_ci16<COUT,PLANE,F2KH,3>(F2CI, fb, wt, cob, off, part);
        for (int ci = F2CI + 1; ci < CIN; ++ci)
            conv_ci16<COUT,PLANE,0,3>(ci, fb, wt, cob, off, part);
    } else {
        for (int ci = F1CI + 1; ci < CIN; ++ci)
            conv_ci16<COUT,PLANE,0,3>(ci, fb, wt, cob, off, part);
    }

#pragma unroll
    for (int c = 0; c < 16; ++c) {
        float4 v = make_float4(__fadd_rn(tot[c*4+0], part[c*4+0]),
                               __fadd_rn(tot[c*4+1], part[c*4+1]),
                               __fadd_rn(tot[c*4+2], part[c*4+2]),
                               __fadd_rn(tot[c*4+3], part[c*4+3]));
        *(float4*)&cur[((uint32_t)(f * COUT + cob + c) * HOUT + hh) * HOUT + 4 * w4] = v;
    }
}

// ------------------------------------------ LIF scan over currents -> spikes
// writes u8 spikes into the PADDED s2p layout (interior only).
template<int COUT, int HW, int HOUTW, int RS, int PLANE>
__global__ __launch_bounds__(256) void lif_s(
    const float* __restrict__ cur, const float* __restrict__ bias,
    uint8_t* __restrict__ spk_p, float alpha, float beta)
{
    const int px = (blockIdx.x * 256 + threadIdx.x) * 4;
    const int co = blockIdx.y;
    const int b  = blockIdx.z;
    const int h  = px / HOUTW, w = px % HOUTW;
    const float bv = bias[co];
    float syn[4] = {0.f,0.f,0.f,0.f}, mem[4] = {0.f,0.f,0.f,0.f};
    for (int t = 0; t < TT; ++t) {
        const int f = t * BB + b;
        float4 v = *(const float4*)&cur[((uint32_t)(f * COUT + co)) * HW + px];
        const float vv[4] = {v.x, v.y, v.z, v.w};
        uint32_t pk = 0;
#pragma unroll
        for (int j = 0; j < 4; ++j) {
            float c = __fadd_rn(vv[j], bv);
            syn[j] = __fadd_rn(__fmul_rn(beta, syn[j]), c);
            mem[j] = __fadd_rn(__fmul_rn(alpha, mem[j]), syn[j]);
            bool sc = (mem[j] >= 1.0f);
            mem[j] = __fsub_rn(mem[j], sc ? 1.0f : 0.0f);
            pk |= (sc ? 1u : 0u) << (j * 8);
        }
        *(uint32_t*)&spk_p[(size_t)(f * COUT + co) * PLANE + (h + 1) * RS + (w + 4)] = pk;
    }
}

// ------------------------------------- LIF + time-mean -> pooled (layer 3)
template<int COUT, int HW>
__global__ __launch_bounds__(256) void lif_mean(
    const float* __restrict__ cur, const float* __restrict__ bias,
    float* __restrict__ pooled, float alpha, float beta)
{
    const int px = (blockIdx.x * 256 + threadIdx.x) * 4;
    const int co = blockIdx.y;
    const int b  = blockIdx.z;
    const float bv = bias[co];
    float syn[4] = {0.f,0.f,0.f,0.f}, mem[4] = {0.f,0.f,0.f,0.f};
    float sum[4] = {0.f,0.f,0.f,0.f};
    for (int t = 0; t < TT; ++t) {
        const int idx = ((t * BB + b) * COUT + co) * HW + px;
        float4 v = *(const float4*)&cur[idx];
        const float vv[4] = {v.x, v.y, v.z, v.w};
#pragma unroll
        for (int j = 0; j < 4; ++j) {
            float c = __fadd_rn(vv[j], bv);
            syn[j] = __fadd_rn(__fmul_rn(beta, syn[j]), c);
            mem[j] = __fadd_rn(__fmul_rn(alpha, mem[j]), syn[j]);
            bool sc = (mem[j] >= 1.0f);
            float sp = sc ? 1.0f : 0.0f;
            mem[j] = __fsub_rn(mem[j], sp);
            sum[j] = __fadd_rn(sum[j], sp);
        }
    }
    *(float4*)&pooled[(b * COUT + co) * HW + px] =
        make_float4(sum[0] / 10.0f, sum[1] / 10.0f, sum[2] / 10.0f, sum[3] / 10.0f);
}

// ------------------------------------------------------------------ det 1x1
__global__ __launch_bounds__(256) void det_conv(
    const float* __restrict__ pooled, // [4,256,1024]
    const float* __restrict__ wd,     // [255,256]
    const float* __restrict__ bd,     // [255]
    float* __restrict__ out)          // [4,255,1024]
{
    __shared__ float wtl[16][64];
    __shared__ float ps[16][64];
    const int tid = threadIdx.x;
    const int b = blockIdx.z;
    const int o_base = blockIdx.y * 64;
    const int px_base = blockIdx.x * 64;
    const int o_off = (tid >> 4) * 4;
    const int px_off = (tid & 15) * 4;
    float acc[4][4];
#pragma unroll
    for (int c = 0; c < 4; ++c) {
        int o = o_base + o_off + c;
        float bv = (o < 255) ? bd[o] : 0.f;
#pragma unroll
        for (int j = 0; j < 4; ++j) acc[c][j] = bv;
    }
    for (int cc = 0; cc < 16; ++cc) {
        for (int k = tid; k < 1024; k += 256) {
            int o = k & 63, ci = k >> 6;
            wtl[ci][o] = (o_base + o < 255) ? wd[(o_base + o) * 256 + cc * 16 + ci] : 0.f;
            ps[ci][o] = pooled[(b * 256 + cc * 16 + ci) * 1024 + px_base + o];
        }
        __syncthreads();
#pragma unroll
        for (int ci = 0; ci < 16; ++ci) {
            float4 wv = *(const float4*)&wtl[ci][o_off];
            float4 sv = *(const float4*)&ps[ci][px_off];
            acc[0][0] += wv.x * sv.x; acc[0][1] += wv.x * sv.y;
            acc[0][2] += wv.x * sv.z; acc[0][3] += wv.x * sv.w;
            acc[1][0] += wv.y * sv.x; acc[1][1] += wv.y * sv.y;
            acc[1][2] += wv.y * sv.z; acc[1][3] += wv.y * sv.w;
            acc[2][0] += wv.z * sv.x; acc[2][1] += wv.z * sv.y;
            acc[2][2] += wv.z * sv.z; acc[2][3] += wv.z * sv.w;
            acc[3][0] += wv.w * sv.x; acc[3][1] += wv.w * sv.y;
            acc[3][2] += wv.w * sv.z; acc[3][3] += wv.w * sv.w;
        }
        __syncthreads();
    }
#pragma unroll
    for (int c = 0; c < 4; ++c) {
        int o = o_base + o_off + c;
        if (o < 255)
            *(float4*)&out[(b * 255 + o) * 1024 + px_base + px_off] =
                make_float4(acc[c][0], acc[c][1], acc[c][2], acc[c][3]);
    }
}

extern "C" void kernel_launch(void* const* d_in, const int* in_sizes, int n_in,
                              void* d_out, int out_size, void* d_ws, size_t ws_size,
                              hipStream_t stream) {
    const float* x  = (const float*)d_in[0];
    const float* w1 = (const float*)d_in[1];
    const float* b1 = (const float*)d_in[2];
    const float* w2 = (const float*)d_in[3];
    const float* b2 = (const float*)d_in[4];
    const float* w3 = (const float*)d_in[5];
    const float* b3 = (const float*)d_in[6];
    const float* wd = (const float*)d_in[7];
    const float* bd = (const float*)d_in[8];
    float* out = (float*)d_out;

    // ws layout (c3 aliases s1p region -- s1p dead after L2 conv):
    //   s1p u8 [2560][17544]  @ 256          (44,912,640)   | c3 f32 41,943,040
    //   s2p u8 [5120][4680]   @ 44,912,896   (23,961,600)
    //   c2  f32 [40*128*4096] @ 68,874,496   (83,886,080)
    //   pooled f32            @ 152,760,576  (4,194,304)
    //   wt2 f32 [576][128]    @ 156,954,880  (294,912)
    //   wt3 f32 [1152][256]   @ 157,249,792  (1,179,648)    end 158,429,440
    uint8_t* wsb = (uint8_t*)d_ws;
    uint8_t* s1p    = wsb + 256;
    float*   c3     = (float*)(wsb + 256);
    uint8_t* s2p    = wsb + 44912896u;
    float*   c2     = (float*)(wsb + 68874496u);
    float*   pooled = (float*)(wsb + 152760576u);
    float*   wt2    = (float*)(wsb + 156954880u);
    float*   wt3    = (float*)(wsb + 157249792u);

    float alpha, beta;
    { uint32_t ab = 0x3F7383C6u; memcpy(&alpha, &ab, 4); }  // e^-0.05f
    { uint32_t bb = 0x3F519857u; memcpy(&beta,  &bb, 4); }  // e^-0.2f

    // zero pad borders (graph-safe, every call)
    zpad<34, 129><<<2560, 256, 0, stream>>>((uint32_t*)s1p);
    zpad<18, 65><<<5120, 256, 0, stream>>>((uint32_t*)s2p);
    wtrans<<<288, 256, 0, stream>>>(w2, wt2, 576, 128);
    wtrans<<<1152, 256, 0, stream>>>(w3, wt3, 1152, 256);
    conv1_lif<<<dim3(16, 128, 4), 256, 0, stream>>>(x, w1, b1, s1p, alpha, beta);
    // L2 conv: 64->128, 128->64. 16co x 4px; block 16 w4 x 16 rows; grid (4,8,40)
    conv_g16<64, 128, 64, 16, 17544, 136, 42, 2, 64, 0>
        <<<dim3(4, 8, 40), 256, 0, stream>>>(s1p, wt2, c2);
    // LIF L2 -> padded s2p spikes
    lif_s<128, 4096, 64, 72, 4680><<<dim3(4, 128, 4), 256, 0, stream>>>(c2, b2, s2p, alpha, beta);
    // L3 conv: 128->256, 64->32. 16co x 4px; block 8 w4 x 32 rows; grid (1,16,40)
    conv_g16<128, 256, 32, 8, 4680, 72, 42, 2, 85, 1>
        <<<dim3(1, 16, 40), 256, 0, stream>>>(s2p, wt3, c3);
    lif_mean<256, 1024><<<dim3(1, 256, 4), 256, 0, stream>>>(c3, b3, pooled, alpha, beta);
    det_conv<<<dim3(16, 4, 4), 256, 0, stream>>>(pooled, wd, bd, out);
}

// Round 14
// 736.735 us; speedup vs baseline: 2.0856x; 2.0856x over previous
//
#include <hip/hip_runtime.h>
#include <hip/hip_fp16.h>
#include <stdint.h>
#include <string.h>
#include <cmath>

// SpikingYOLO round 14: recover from R13 spill (128 acc = scratch disaster;
// 64 acc is the ceiling) -> back to 8co x 4px, plus f16 spike planes consumed
// via v_fma_mix_f32 (fmaf((float)h, w, acc) pattern): kills the 9 cvt/window
// and one load. Numerics BIT-IDENTICAL to R9-R13: FMA-sequential f32 conv,
// k=(ci,kh,kw) ascending, kc=384 flushes at k=384/768, bias after, unfused
// f32 LIF, alpha=0x3F7383C6 beta=0x3F519857. f16 holds spikes {0,1} exactly.

#define BB 4
#define TT 10

// f16 padded plane geometry: left pad 1 col, top pad 1 row.
// L2 input (s1phf): 128x128 -> rows 129, row 136 halves (272B), plane 17544 halves
// L3 input (s2phf): 64x64   -> rows 65,  row 72 halves (144B),  plane 4680 halves

static __device__ __forceinline__ __half2 u2h2(uint32_t u) {
    __half2 r; memcpy(&r, &u, 4); return r;
}

// ------------------------------------------------ zero the f16 pad borders
template<int RS_H, int NROWS>
__global__ __launch_bounds__(256) void zpad_h(uint16_t* __restrict__ buf) {
    uint16_t* p = buf + (size_t)blockIdx.x * (RS_H * NROWS);
    for (int i = threadIdx.x; i < NROWS + RS_H; i += 256) {
        if (i < NROWS) p[i * RS_H] = 0;      // left pad col of every row
        else           p[i - NROWS] = 0;     // top pad row
    }
}

// ---------------------------------------------------------------- conv1+LIF
// unchanged numerics from R9; writes f16 spikes into padded s1phf layout.
__global__ __launch_bounds__(256) void conv1_lif(
    const float* __restrict__ x,    // [4,2,128,128,10]
    const float* __restrict__ w1,   // [64,2,3,3]
    const float* __restrict__ b1,   // [64]
    uint16_t* __restrict__ s1phf,   // padded f16 [40*64][129][136]
    float alpha, float beta)
{
    __shared__ float xs[2][3][10][10];   // [ci][kh][wi][t]
    __shared__ float wsh[18][64];        // [tap][co]
    const int tid = threadIdx.x;
    const int b = blockIdx.z, h = blockIdx.y, w0 = blockIdx.x * 8;

    for (int i = tid; i < 1152; i += 256) {
        int co = i & 63, tap = i >> 6;
        wsh[tap][co] = w1[co * 18 + tap];
    }
    for (int i = tid; i < 600; i += 256) {
        int t = i % 10; int rest = i / 10;
        int wi = rest % 10; rest /= 10;
        int kh = rest % 3; int ci = rest / 3;
        int hh = h - 1 + kh, ww = w0 - 1 + wi;
        float v = 0.f;
        if (hh >= 0 && hh < 128 && ww >= 0 && ww < 128)
            v = x[(((b * 2 + ci) * 128 + hh) * 128 + ww) * 10 + t];
        xs[ci][kh][wi][t] = v;
    }
    __syncthreads();

    const int px  = tid & 7;
    const int cog = (tid >> 3) * 2;
    float acc[2][10];
#pragma unroll
    for (int c = 0; c < 2; ++c)
#pragma unroll
        for (int t = 0; t < 10; ++t) acc[c][t] = 0.f;

#pragma unroll
    for (int tap = 0; tap < 18; ++tap) {
        const int ci = tap / 9, kh = (tap % 9) / 3, kw = tap % 3;
        float2 wv = *(const float2*)&wsh[tap][cog];
#pragma unroll
        for (int t = 0; t < 10; ++t) {
            float xv = xs[ci][kh][px + kw][t];
            acc[0][t] = __fmaf_rn(wv.x, xv, acc[0][t]);
            acc[1][t] = __fmaf_rn(wv.y, xv, acc[1][t]);
        }
    }
#pragma unroll
    for (int c = 0; c < 2; ++c) {
        const float bv = b1[cog + c];
        float syn = 0.f, mem = 0.f;
#pragma unroll
        for (int t = 0; t < 10; ++t) {
            float cur = __fadd_rn(acc[c][t], bv);
            syn = __fadd_rn(__fmul_rn(beta, syn), cur);
            mem = __fadd_rn(__fmul_rn(alpha, mem), syn);
            bool sc = (mem >= 1.0f);
            mem = __fsub_rn(mem, sc ? 1.0f : 0.0f);
            s1phf[(size_t)((t * BB + b) * 64 + (cog + c)) * 17544u
                  + (h + 1) * 136 + (w0 + px + 1)] = sc ? 0x3C00 : 0;
        }
    }
}

// --------------------------------------------------- weight transpose kernel
__global__ __launch_bounds__(256) void wtrans(
    const float* __restrict__ w, float* __restrict__ wt, int K, int COUT)
{
    int i = blockIdx.x * 256 + threadIdx.x;
    if (i < K * COUT) {
        int k = i / COUT, co = i - k * COUT;
        wt[i] = w[co * K + k];
    }
}

// ------------------------------------------------- per-ci conv taps (inlined)
// 8co x 4px; f16 padded input; sv[c] = spike at in-col 8w4-1+c.
template<int COUT, int PLANE_H, int KHB, int KHE>
__device__ __forceinline__ void conv_ci8h(
    int ci, const uint16_t* __restrict__ fb, const float* __restrict__ wt,
    int cob, const int off[3], float part[32])
{
    const uint16_t* p = fb + (uint32_t)ci * PLANE_H;
    uint4 va[3]; uint32_t vb[3];
#pragma unroll
    for (int kh = KHB; kh < KHE; ++kh) {
        const uint16_t* q = p + off[kh];
        va[kh] = *(const uint4*)q;           // 16B aligned (off = 8*w4 + row*136)
        vb[kh] = *(const uint32_t*)(q + 8);
    }
#pragma unroll
    for (int kh = KHB; kh < KHE; ++kh) {
        __half2 h0 = u2h2(va[kh].x), h1 = u2h2(va[kh].y),
                h2 = u2h2(va[kh].z), h3 = u2h2(va[kh].w), h4 = u2h2(vb[kh]);
        float sv[9];
        sv[0] = __low2float(h0);  sv[1] = __high2float(h0);
        sv[2] = __low2float(h1);  sv[3] = __high2float(h1);
        sv[4] = __low2float(h2);  sv[5] = __high2float(h2);
        sv[6] = __low2float(h3);  sv[7] = __high2float(h3);
        sv[8] = __low2float(h4);
#pragma unroll
        for (int kw = 0; kw < 3; ++kw) {
            const float* wp = wt + (ci * 9 + kh * 3 + kw) * COUT + cob; // uniform -> s_load
#pragma unroll
            for (int co = 0; co < 8; ++co) {
                const float wv = wp[co];
#pragma unroll
                for (int j = 0; j < 4; ++j)
                    part[co * 4 + j] = __fmaf_rn(wv, sv[2 * j + kw], part[co * 4 + j]);
            }
        }
    }
}

// -------------------- stride-2 3x3 conv, t-parallel, currents out (no LIF)
template<int CIN, int COUT, int HOUT, int WTH, int PLANE_H, int RS_H,
         int F1CI, int F1KH, int F2CI, int F2KH>
__global__ __launch_bounds__(256) void conv_g8h(
    const uint16_t* __restrict__ sin,  // padded f16 planes [40*CIN][...]
    const float* __restrict__ wt,      // [CIN*9][COUT] transposed
    float* __restrict__ cur)           // [40,COUT,HOUT,HOUT] pre-bias currents
{
    const int tid = threadIdx.x;
    const int w4  = tid & (WTH - 1);
    const int hh  = blockIdx.x * (256 / WTH) + (tid / WTH);
    const int cob = blockIdx.y * 8;
    const int f   = blockIdx.z;

    const uint16_t* fb = sin + (size_t)f * CIN * PLANE_H;
    int off[3];
#pragma unroll
    for (int kh = 0; kh < 3; ++kh) off[kh] = (2 * hh + kh) * RS_H + 8 * w4;

    float part[32], tot[32];
#pragma unroll
    for (int n = 0; n < 32; ++n) { part[n] = 0.f; tot[n] = 0.f; }

    for (int ci = 0; ci < F1CI; ++ci)
        conv_ci8h<COUT,PLANE_H,0,3>(ci, fb, wt, cob, off, part);
    // kc flush #1 at global k=384
    conv_ci8h<COUT,PLANE_H,0,F1KH>(F1CI, fb, wt, cob, off, part);
#pragma unroll
    for (int n = 0; n < 32; ++n) { tot[n] = __fadd_rn(tot[n], part[n]); part[n] = 0.f; }
    conv_ci8h<COUT,PLANE_H,F1KH,3>(F1CI, fb, wt, cob, off, part);
    if constexpr (F2CI < CIN) {
        for (int ci = F1CI + 1; ci < F2CI; ++ci)
            conv_ci8h<COUT,PLANE_H,0,3>(ci, fb, wt, cob, off, part);
        // kc flush #2 at global k=768
        conv_ci8h<COUT,PLANE_H,0,F2KH>(F2CI, fb, wt, cob, off, part);
#pragma unroll
        for (int n = 0; n < 32; ++n) { tot[n] = __fadd_rn(tot[n], part[n]); part[n] = 0.f; }
        conv_ci8h<COUT,PLANE_H,F2KH,3>(F2CI, fb, wt, cob, off, part);
        for (int ci = F2CI + 1; ci < CIN; ++ci)
            conv_ci8h<COUT,PLANE_H,0,3>(ci, fb, wt, cob, off, part);
    } else {
        for (int ci = F1CI + 1; ci < CIN; ++ci)
            conv_ci8h<COUT,PLANE_H,0,3>(ci, fb, wt, cob, off, part);
    }

#pragma unroll
    for (int c = 0; c < 8; ++c) {
        float4 v = make_float4(__fadd_rn(tot[c*4+0], part[c*4+0]),
                               __fadd_rn(tot[c*4+1], part[c*4+1]),
                               __fadd_rn(tot[c*4+2], part[c*4+2]),
                               __fadd_rn(tot[c*4+3], part[c*4+3]));
        *(float4*)&cur[((uint32_t)(f * COUT + cob + c) * HOUT + hh) * HOUT + 4 * w4] = v;
    }
}

// ------------------------------------------ LIF scan over currents -> spikes
// writes f16 spikes into the PADDED s2phf layout (interior only).
template<int COUT, int HW, int HOUTW, int RS_H, int PLANE_H>
__global__ __launch_bounds__(256) void lif_s(
    const float* __restrict__ cur, const float* __restrict__ bias,
    uint16_t* __restrict__ spk_h, float alpha, float beta)
{
    const int px = (blockIdx.x * 256 + threadIdx.x) * 4;
    const int co = blockIdx.y;
    const int b  = blockIdx.z;
    const int h  = px / HOUTW, w = px % HOUTW;
    const float bv = bias[co];
    float syn[4] = {0.f,0.f,0.f,0.f}, mem[4] = {0.f,0.f,0.f,0.f};
    for (int t = 0; t < TT; ++t) {
        const int f = t * BB + b;
        float4 v = *(const float4*)&cur[((uint32_t)(f * COUT + co)) * HW + px];
        const float vv[4] = {v.x, v.y, v.z, v.w};
        uint16_t* o = spk_h + (size_t)(f * COUT + co) * PLANE_H + (h + 1) * RS_H + (w + 1);
#pragma unroll
        for (int j = 0; j < 4; ++j) {
            float c = __fadd_rn(vv[j], bv);
            syn[j] = __fadd_rn(__fmul_rn(beta, syn[j]), c);
            mem[j] = __fadd_rn(__fmul_rn(alpha, mem[j]), syn[j]);
            bool sc = (mem[j] >= 1.0f);
            mem[j] = __fsub_rn(mem[j], sc ? 1.0f : 0.0f);
            o[j] = sc ? 0x3C00 : 0;
        }
    }
}

// ------------------------------------- LIF + time-mean -> pooled (layer 3)
template<int COUT, int HW>
__global__ __launch_bounds__(256) void lif_mean(
    const float* __restrict__ cur, const float* __restrict__ bias,
    float* __restrict__ pooled, float alpha, float beta)
{
    const int px = (blockIdx.x * 256 + threadIdx.x) * 4;
    const int co = blockIdx.y;
    const int b  = blockIdx.z;
    const float bv = bias[co];
    float syn[4] = {0.f,0.f,0.f,0.f}, mem[4] = {0.f,0.f,0.f,0.f};
    float sum[4] = {0.f,0.f,0.f,0.f};
    for (int t = 0; t < TT; ++t) {
        const int idx = ((t * BB + b) * COUT + co) * HW + px;
        float4 v = *(const float4*)&cur[idx];
        const float vv[4] = {v.x, v.y, v.z, v.w};
#pragma unroll
        for (int j = 0; j < 4; ++j) {
            float c = __fadd_rn(vv[j], bv);
            syn[j] = __fadd_rn(__fmul_rn(beta, syn[j]), c);
            mem[j] = __fadd_rn(__fmul_rn(alpha, mem[j]), syn[j]);
            bool sc = (mem[j] >= 1.0f);
            float sp = sc ? 1.0f : 0.0f;
            mem[j] = __fsub_rn(mem[j], sp);
            sum[j] = __fadd_rn(sum[j], sp);
        }
    }
    *(float4*)&pooled[(b * COUT + co) * HW + px] =
        make_float4(sum[0] / 10.0f, sum[1] / 10.0f, sum[2] / 10.0f, sum[3] / 10.0f);
}

// ------------------------------------------------------------------ det 1x1
__global__ __launch_bounds__(256) void det_conv(
    const float* __restrict__ pooled, // [4,256,1024]
    const float* __restrict__ wd,     // [255,256]
    const float* __restrict__ bd,     // [255]
    float* __restrict__ out)          // [4,255,1024]
{
    __shared__ float wtl[16][64];
    __shared__ float ps[16][64];
    const int tid = threadIdx.x;
    const int b = blockIdx.z;
    const int o_base = blockIdx.y * 64;
    const int px_base = blockIdx.x * 64;
    const int o_off = (tid >> 4) * 4;
    const int px_off = (tid & 15) * 4;
    float acc[4][4];
#pragma unroll
    for (int c = 0; c < 4; ++c) {
        int o = o_base + o_off + c;
        float bv = (o < 255) ? bd[o] : 0.f;
#pragma unroll
        for (int j = 0; j < 4; ++j) acc[c][j] = bv;
    }
    for (int cc = 0; cc < 16; ++cc) {
        for (int k = tid; k < 1024; k += 256) {
            int o = k & 63, ci = k >> 6;
            wtl[ci][o] = (o_base + o < 255) ? wd[(o_base + o) * 256 + cc * 16 + ci] : 0.f;
            ps[ci][o] = pooled[(b * 256 + cc * 16 + ci) * 1024 + px_base + o];
        }
        __syncthreads();
#pragma unroll
        for (int ci = 0; ci < 16; ++ci) {
            float4 wv = *(const float4*)&wtl[ci][o_off];
            float4 sv = *(const float4*)&ps[ci][px_off];
            acc[0][0] += wv.x * sv.x; acc[0][1] += wv.x * sv.y;
            acc[0][2] += wv.x * sv.z; acc[0][3] += wv.x * sv.w;
            acc[1][0] += wv.y * sv.x; acc[1][1] += wv.y * sv.y;
            acc[1][2] += wv.y * sv.z; acc[1][3] += wv.y * sv.w;
            acc[2][0] += wv.z * sv.x; acc[2][1] += wv.z * sv.y;
            acc[2][2] += wv.z * sv.z; acc[2][3] += wv.z * sv.w;
            acc[3][0] += wv.w * sv.x; acc[3][1] += wv.w * sv.y;
            acc[3][2] += wv.w * sv.z; acc[3][3] += wv.w * sv.w;
        }
        __syncthreads();
    }
#pragma unroll
    for (int c = 0; c < 4; ++c) {
        int o = o_base + o_off + c;
        if (o < 255)
            *(float4*)&out[(b * 255 + o) * 1024 + px_base + px_off] =
                make_float4(acc[c][0], acc[c][1], acc[c][2], acc[c][3]);
    }
}

extern "C" void kernel_launch(void* const* d_in, const int* in_sizes, int n_in,
                              void* d_out, int out_size, void* d_ws, size_t ws_size,
                              hipStream_t stream) {
    const float* x  = (const float*)d_in[0];
    const float* w1 = (const float*)d_in[1];
    const float* b1 = (const float*)d_in[2];
    const float* w2 = (const float*)d_in[3];
    const float* b2 = (const float*)d_in[4];
    const float* w3 = (const float*)d_in[5];
    const float* b3 = (const float*)d_in[6];
    const float* wd = (const float*)d_in[7];
    const float* bd = (const float*)d_in[8];
    float* out = (float*)d_out;

    // ws layout (aliases: c3 over s1phf -- dead after L2 conv; pooled over c2
    // -- dead after lif_s):
    //   s1phf f16 [2560][17544]  @ 256          (89,825,280)  | c3 f32 41.9MB
    //   s2phf f16 [5120][4680]   @ 89,825,536   (47,923,200)
    //   c2    f32 [40*128*4096]  @ 137,748,736  (83,886,080)  | pooled 4.2MB
    //   wt2   f32 [576][128]     @ 221,634,816  (294,912)
    //   wt3   f32 [1152][256]    @ 221,929,728  (1,179,648)   end 223,109,376
    uint8_t* wsb = (uint8_t*)d_ws;
    uint16_t* s1phf = (uint16_t*)(wsb + 256);
    float*    c3    = (float*)(wsb + 256);
    uint16_t* s2phf = (uint16_t*)(wsb + 89825536u);
    float*    c2    = (float*)(wsb + 137748736u);
    float*    pooled= (float*)(wsb + 137748736u);
    float*    wt2   = (float*)(wsb + 221634816u);
    float*    wt3   = (float*)(wsb + 221929728u);

    float alpha, beta;
    { uint32_t ab = 0x3F7383C6u; memcpy(&alpha, &ab, 4); }  // e^-0.05f
    { uint32_t bb = 0x3F519857u; memcpy(&beta,  &bb, 4); }  // e^-0.2f

    zpad_h<136, 129><<<2560, 256, 0, stream>>>(s1phf);
    zpad_h<72, 65><<<5120, 256, 0, stream>>>(s2phf);
    wtrans<<<288, 256, 0, stream>>>(w2, wt2, 576, 128);
    wtrans<<<1152, 256, 0, stream>>>(w3, wt3, 1152, 256);
    conv1_lif<<<dim3(16, 128, 4), 256, 0, stream>>>(x, w1, b1, s1phf, alpha, beta);
    // L2 conv: 64->128, 128->64. 8co x 4px; grid (4,16,40)
    conv_g8h<64, 128, 64, 16, 17544, 136, 42, 2, 64, 0>
        <<<dim3(4, 16, 40), 256, 0, stream>>>(s1phf, wt2, c2);
    lif_s<128, 4096, 64, 72, 4680><<<dim3(4, 128, 4), 256, 0, stream>>>(c2, b2, s2phf, alpha, beta);
    // L3 conv: 128->256, 64->32. 8co x 4px; grid (1,32,40)
    conv_g8h<128, 256, 32, 8, 4680, 72, 42, 2, 85, 1>
        <<<dim3(1, 32, 40), 256, 0, stream>>>(s2phf, wt3, c3);
    lif_mean<256, 1024><<<dim3(1, 256, 4), 256, 0, stream>>>(c3, b3, pooled, alpha, beta);
    det_conv<<<dim3(16, 4, 4), 256, 0, stream>>>(pooled, wd, bd, out);
}

// Round 15
// 707.381 us; speedup vs baseline: 2.1721x; 1.0415x over previous
//
#include <hip/hip_runtime.h>
#include <stdint.h>
#include <string.h>
#include <cmath>

// SpikingYOLO round 15: chain-split parallelism from the kc=384 association.
// Reference semantics (settled R9): conv = ((P1+P2)+P3), each Pi an independent
// zero-init FMA chain over k-ranges split at 384/768, k=(ci,kh,kw) ascending;
// bias after; unfused f32 LIF; alpha=0x3F7383C6 beta=0x3F519857.
// Independent chains -> independent BLOCKS: L3 conv (K=1152) runs as 3 chains
// (grid z = chain*40+f, 1920 blocks, 16co x 4px, part[64] only -- 64 live acc,
// R12-proven safe; R13's 128 spilled). lif_mean3 combines fadd(fadd(P1,P2),P3)
// -> bit-identical. L2 conv = R12's exact u8 conv_g8 (f16 experiment reverted:
// R14 was neutral-negative, FETCH doubled).

#define BB 4
#define TT 10

// padded u8 plane geometry: rows -1..HIN-1 (HIN+1 rows), cols -4..HIN+3 (HIN+8)
// L2 input (s1p): HIN=128: row stride 136 B, plane 129*136 = 17544 B
// L3 input (s2p): HIN=64 : row stride 72 B,  plane 65*72   = 4680 B

// ------------------------------------------------ zero the pad borders
template<int RS_DW, int NROWS>
__global__ __launch_bounds__(256) void zpad(uint32_t* __restrict__ buf) {
    const int plane = blockIdx.x;
    const int j = threadIdx.x;
    uint32_t* p = buf + (size_t)plane * (RS_DW * NROWS);
    if (j < NROWS) p[j * RS_DW] = 0u;                    // cols -4..-1 of every row
    const int k = j - NROWS;
    if (k >= 0 && k < RS_DW - 1) p[k + 1] = 0u;          // rest of top pad row (-1)
}

// ---------------------------------------------------------------- conv1+LIF
// unchanged numerics from R9; writes u8 spikes into padded s1p layout.
__global__ __launch_bounds__(256) void conv1_lif(
    const float* __restrict__ x,    // [4,2,128,128,10]
    const float* __restrict__ w1,   // [64,2,3,3]
    const float* __restrict__ b1,   // [64]
    uint8_t* __restrict__ s1p,      // padded [40*64][129][136]
    float alpha, float beta)
{
    __shared__ float xs[2][3][10][10];   // [ci][kh][wi][t]
    __shared__ float wsh[18][64];        // [tap][co]
    const int tid = threadIdx.x;
    const int b = blockIdx.z, h = blockIdx.y, w0 = blockIdx.x * 8;

    for (int i = tid; i < 1152; i += 256) {
        int co = i & 63, tap = i >> 6;
        wsh[tap][co] = w1[co * 18 + tap];
    }
    for (int i = tid; i < 600; i += 256) {
        int t = i % 10; int rest = i / 10;
        int wi = rest % 10; rest /= 10;
        int kh = rest % 3; int ci = rest / 3;
        int hh = h - 1 + kh, ww = w0 - 1 + wi;
        float v = 0.f;
        if (hh >= 0 && hh < 128 && ww >= 0 && ww < 128)
            v = x[(((b * 2 + ci) * 128 + hh) * 128 + ww) * 10 + t];
        xs[ci][kh][wi][t] = v;
    }
    __syncthreads();

    const int px  = tid & 7;
    const int cog = (tid >> 3) * 2;
    float acc[2][10];
#pragma unroll
    for (int c = 0; c < 2; ++c)
#pragma unroll
        for (int t = 0; t < 10; ++t) acc[c][t] = 0.f;

#pragma unroll
    for (int tap = 0; tap < 18; ++tap) {
        const int ci = tap / 9, kh = (tap % 9) / 3, kw = tap % 3;
        float2 wv = *(const float2*)&wsh[tap][cog];
#pragma unroll
        for (int t = 0; t < 10; ++t) {
            float xv = xs[ci][kh][px + kw][t];
            acc[0][t] = __fmaf_rn(wv.x, xv, acc[0][t]);
            acc[1][t] = __fmaf_rn(wv.y, xv, acc[1][t]);
        }
    }
#pragma unroll
    for (int c = 0; c < 2; ++c) {
        const float bv = b1[cog + c];
        float syn = 0.f, mem = 0.f;
#pragma unroll
        for (int t = 0; t < 10; ++t) {
            float cur = __fadd_rn(acc[c][t], bv);
            syn = __fadd_rn(__fmul_rn(beta, syn), cur);
            mem = __fadd_rn(__fmul_rn(alpha, mem), syn);
            float sp = (mem >= 1.0f) ? 1.0f : 0.0f;
            mem = __fsub_rn(mem, sp);
            s1p[(uint32_t)((t * BB + b) * 64 + (cog + c)) * 17544u
                + (h + 1) * 136 + (w0 + px + 4)] = (uint8_t)sp;
        }
    }
}

// --------------------------------------------------- weight transpose kernel
__global__ __launch_bounds__(256) void wtrans(
    const float* __restrict__ w, float* __restrict__ wt, int K, int COUT)
{
    int i = blockIdx.x * 256 + threadIdx.x;
    if (i < K * COUT) {
        int k = i / COUT, co = i - k * COUT;
        wt[i] = w[co * K + k];
    }
}

// ---------------------------------------- per-ci conv taps, 8co x 4px (R12)
template<int COUT, int PLANE, int KHB, int KHE>
__device__ __forceinline__ void conv_ci8(
    int ci, const uint8_t* __restrict__ fb, const float* __restrict__ wt,
    int cob, const int off[3], float part[32])
{
    const uint8_t* p = fb + (uint32_t)ci * PLANE;
    uint32_t d0[3], d1[3], d2[3];
#pragma unroll
    for (int kh = KHB; kh < KHE; ++kh) {
        const uint8_t* q = p + off[kh];
        uint2 v = *(const uint2*)q;
        d0[kh] = v.x; d1[kh] = v.y;
        d2[kh] = *(const uint32_t*)(q + 8);
    }
#pragma unroll
    for (int kh = KHB; kh < KHE; ++kh) {
        float sv[9];
        sv[0] = (float)(d0[kh] >> 24);
        sv[1] = (float)(d1[kh] & 0xffu);
        sv[2] = (float)((d1[kh] >> 8) & 0xffu);
        sv[3] = (float)((d1[kh] >> 16) & 0xffu);
        sv[4] = (float)(d1[kh] >> 24);
        sv[5] = (float)(d2[kh] & 0xffu);
        sv[6] = (float)((d2[kh] >> 8) & 0xffu);
        sv[7] = (float)((d2[kh] >> 16) & 0xffu);
        sv[8] = (float)(d2[kh] >> 24);
#pragma unroll
        for (int kw = 0; kw < 3; ++kw) {
            const float* wp = wt + (ci * 9 + kh * 3 + kw) * COUT + cob; // uniform -> s_load
#pragma unroll
            for (int co = 0; co < 8; ++co) {
                const float wv = wp[co];
#pragma unroll
                for (int j = 0; j < 4; ++j)
                    part[co * 4 + j] = __fmaf_rn(wv, sv[2 * j + kw], part[co * 4 + j]);
            }
        }
    }
}

// -------------------------------- per-ci conv taps, 16co x 4px (for chains)
template<int COUT, int PLANE, int KHB, int KHE>
__device__ __forceinline__ void conv_ci16(
    int ci, const uint8_t* __restrict__ fb, const float* __restrict__ wt,
    int cob, const int off[3], float part[64])
{
    const uint8_t* p = fb + (uint32_t)ci * PLANE;
    uint32_t d0[3], d1[3], d2[3];
#pragma unroll
    for (int kh = KHB; kh < KHE; ++kh) {
        const uint8_t* q = p + off[kh];
        uint2 v = *(const uint2*)q;
        d0[kh] = v.x; d1[kh] = v.y;
        d2[kh] = *(const uint32_t*)(q + 8);
    }
#pragma unroll
    for (int kh = KHB; kh < KHE; ++kh) {
        float sv[9];
        sv[0] = (float)(d0[kh] >> 24);
        sv[1] = (float)(d1[kh] & 0xffu);
        sv[2] = (float)((d1[kh] >> 8) & 0xffu);
        sv[3] = (float)((d1[kh] >> 16) & 0xffu);
        sv[4] = (float)(d1[kh] >> 24);
        sv[5] = (float)(d2[kh] & 0xffu);
        sv[6] = (float)((d2[kh] >> 8) & 0xffu);
        sv[7] = (float)((d2[kh] >> 16) & 0xffu);
        sv[8] = (float)(d2[kh] >> 24);
#pragma unroll
        for (int kw = 0; kw < 3; ++kw) {
            const float* wp = wt + (ci * 9 + kh * 3 + kw) * COUT + cob; // uniform -> s_load_dwordx16
#pragma unroll
            for (int co = 0; co < 16; ++co) {
                const float wv = wp[co];
#pragma unroll
                for (int j = 0; j < 4; ++j)
                    part[co * 4 + j] = __fmaf_rn(wv, sv[2 * j + kw], part[co * 4 + j]);
            }
        }
    }
}

// -------------------- L2 conv (R12 exact): 2 chains in-thread, 8co x 4px
template<int CIN, int COUT, int HOUT, int WTH, int PLANE, int RS,
         int F1CI, int F1KH>
__global__ __launch_bounds__(256) void conv_g8(
    const uint8_t* __restrict__ sin,   // padded planes [40*CIN][...]
    const float* __restrict__ wt,      // [CIN*9][COUT] transposed
    float* __restrict__ cur)           // [40,COUT,HOUT,HOUT] pre-bias currents
{
    const int tid = threadIdx.x;
    const int w4  = tid & (WTH - 1);
    const int hh  = blockIdx.x * (256 / WTH) + (tid / WTH);
    const int cob = blockIdx.y * 8;
    const int f   = blockIdx.z;

    const uint8_t* fb = sin + (size_t)f * CIN * PLANE;
    int off[3];
#pragma unroll
    for (int kh = 0; kh < 3; ++kh) off[kh] = (2 * hh + kh) * RS + 8 * w4;

    float part[32], tot[32];
#pragma unroll
    for (int n = 0; n < 32; ++n) { part[n] = 0.f; tot[n] = 0.f; }

    for (int ci = 0; ci < F1CI; ++ci)
        conv_ci8<COUT,PLANE,0,3>(ci, fb, wt, cob, off, part);
    // kc flush #1 at global k=384
    conv_ci8<COUT,PLANE,0,F1KH>(F1CI, fb, wt, cob, off, part);
#pragma unroll
    for (int n = 0; n < 32; ++n) { tot[n] = __fadd_rn(tot[n], part[n]); part[n] = 0.f; }
    conv_ci8<COUT,PLANE,F1KH,3>(F1CI, fb, wt, cob, off, part);
    for (int ci = F1CI + 1; ci < CIN; ++ci)
        conv_ci8<COUT,PLANE,0,3>(ci, fb, wt, cob, off, part);

#pragma unroll
    for (int c = 0; c < 8; ++c) {
        float4 v = make_float4(__fadd_rn(tot[c*4+0], part[c*4+0]),
                               __fadd_rn(tot[c*4+1], part[c*4+1]),
                               __fadd_rn(tot[c*4+2], part[c*4+2]),
                               __fadd_rn(tot[c*4+3], part[c*4+3]));
        *(float4*)&cur[((uint32_t)(f * COUT + cob + c) * HOUT + hh) * HOUT + 4 * w4] = v;
    }
}

// ------------------- L3 conv, chain-split: one block computes ONE chain.
// chains (global k split at 384=ci42,kh2 and 768=ci85,kh1):
//   chain0: ci 0..41 full + ci42 kh{0,1}
//   chain1: ci42 kh2 + ci 43..84 full + ci85 kh0
//   chain2: ci85 kh{1,2} + ci 86..127 full
// 16co x 4px, part[64] only (64 live acc = R12-safe level).
__global__ __launch_bounds__(256) void conv3_chains(
    const uint8_t* __restrict__ sin,   // s2p padded [40*128][65][72]
    const float* __restrict__ wt,      // [1152][256]
    float* __restrict__ p0, float* __restrict__ p1, float* __restrict__ p2)
{
    const int tid = threadIdx.x;
    const int zc  = blockIdx.z / 40;
    const int f   = blockIdx.z - zc * 40;
    const int w4  = tid & 7;
    const int hh  = tid >> 3;            // 32 rows per block (full 32x32 out)
    const int cob = blockIdx.y * 16;

    const uint8_t* fb = sin + (size_t)f * 128 * 4680;
    int off[3];
#pragma unroll
    for (int kh = 0; kh < 3; ++kh) off[kh] = (2 * hh + kh) * 72 + 8 * w4;

    float part[64];
#pragma unroll
    for (int n = 0; n < 64; ++n) part[n] = 0.f;

    float* outp;
    if (zc == 0) {
        for (int ci = 0; ci < 42; ++ci)
            conv_ci16<256,4680,0,3>(ci, fb, wt, cob, off, part);
        conv_ci16<256,4680,0,2>(42, fb, wt, cob, off, part);
        outp = p0;
    } else if (zc == 1) {
        conv_ci16<256,4680,2,3>(42, fb, wt, cob, off, part);
        for (int ci = 43; ci < 85; ++ci)
            conv_ci16<256,4680,0,3>(ci, fb, wt, cob, off, part);
        conv_ci16<256,4680,0,1>(85, fb, wt, cob, off, part);
        outp = p1;
    } else {
        conv_ci16<256,4680,1,3>(85, fb, wt, cob, off, part);
        for (int ci = 86; ci < 128; ++ci)
            conv_ci16<256,4680,0,3>(ci, fb, wt, cob, off, part);
        outp = p2;
    }

#pragma unroll
    for (int c = 0; c < 16; ++c)
        *(float4*)&outp[((uint32_t)(f * 256 + cob + c) * 32 + hh) * 32 + 4 * w4] =
            make_float4(part[c*4+0], part[c*4+1], part[c*4+2], part[c*4+3]);
}

// ------------------------------------------ LIF scan over currents -> spikes
// writes u8 spikes into the PADDED s2p layout (interior only).
template<int COUT, int HW, int HOUTW, int RS, int PLANE>
__global__ __launch_bounds__(256) void lif_s(
    const float* __restrict__ cur, const float* __restrict__ bias,
    uint8_t* __restrict__ spk_p, float alpha, float beta)
{
    const int px = (blockIdx.x * 256 + threadIdx.x) * 4;
    const int co = blockIdx.y;
    const int b  = blockIdx.z;
    const int h  = px / HOUTW, w = px % HOUTW;
    const float bv = bias[co];
    float syn[4] = {0.f,0.f,0.f,0.f}, mem[4] = {0.f,0.f,0.f,0.f};
    for (int t = 0; t < TT; ++t) {
        const int f = t * BB + b;
        float4 v = *(const float4*)&cur[((uint32_t)(f * COUT + co)) * HW + px];
        const float vv[4] = {v.x, v.y, v.z, v.w};
        uint32_t pk = 0;
#pragma unroll
        for (int j = 0; j < 4; ++j) {
            float c = __fadd_rn(vv[j], bv);
            syn[j] = __fadd_rn(__fmul_rn(beta, syn[j]), c);
            mem[j] = __fadd_rn(__fmul_rn(alpha, mem[j]), syn[j]);
            bool sc = (mem[j] >= 1.0f);
            mem[j] = __fsub_rn(mem[j], sc ? 1.0f : 0.0f);
            pk |= (sc ? 1u : 0u) << (j * 8);
        }
        *(uint32_t*)&spk_p[(size_t)(f * COUT + co) * PLANE + (h + 1) * RS + (w + 4)] = pk;
    }
}

// ---------------------- LIF + time-mean from 3 chain partials (layer 3)
// conv = fadd(fadd(P1,P2),P3) == R12's fadd(fadd(fadd(0,P1),P2),P3). Bit-exact.
__global__ __launch_bounds__(256) void lif_mean3(
    const float* __restrict__ p0, const float* __restrict__ p1,
    const float* __restrict__ p2, const float* __restrict__ bias,
    float* __restrict__ pooled, float alpha, float beta)
{
    const int px = (blockIdx.x * 256 + threadIdx.x) * 4;
    const int co = blockIdx.y;
    const int b  = blockIdx.z;
    const float bv = bias[co];
    float syn[4] = {0.f,0.f,0.f,0.f}, mem[4] = {0.f,0.f,0.f,0.f};
    float sum[4] = {0.f,0.f,0.f,0.f};
    for (int t = 0; t < TT; ++t) {
        const int idx = ((t * BB + b) * 256 + co) * 1024 + px;
        float4 a = *(const float4*)&p0[idx];
        float4 c = *(const float4*)&p1[idx];
        float4 d = *(const float4*)&p2[idx];
        const float va[4] = {a.x, a.y, a.z, a.w};
        const float vc[4] = {c.x, c.y, c.z, c.w};
        const float vd[4] = {d.x, d.y, d.z, d.w};
#pragma unroll
        for (int j = 0; j < 4; ++j) {
            float conv = __fadd_rn(__fadd_rn(va[j], vc[j]), vd[j]);
            float cu = __fadd_rn(conv, bv);
            syn[j] = __fadd_rn(__fmul_rn(beta, syn[j]), cu);
            mem[j] = __fadd_rn(__fmul_rn(alpha, mem[j]), syn[j]);
            bool sc = (mem[j] >= 1.0f);
            float sp = sc ? 1.0f : 0.0f;
            mem[j] = __fsub_rn(mem[j], sp);
            sum[j] = __fadd_rn(sum[j], sp);
        }
    }
    *(float4*)&pooled[(b * 256 + co) * 1024 + px] =
        make_float4(sum[0] / 10.0f, sum[1] / 10.0f, sum[2] / 10.0f, sum[3] / 10.0f);
}

// ------------------------------------------------------------------ det 1x1
__global__ __launch_bounds__(256) void det_conv(
    const float* __restrict__ pooled, // [4,256,1024]
    const float* __restrict__ wd,     // [255,256]
    const float* __restrict__ bd,     // [255]
    float* __restrict__ out)          // [4,255,1024]
{
    __shared__ float wtl[16][64];
    __shared__ float ps[16][64];
    const int tid = threadIdx.x;
    const int b = blockIdx.z;
    const int o_base = blockIdx.y * 64;
    const int px_base = blockIdx.x * 64;
    const int o_off = (tid >> 4) * 4;
    const int px_off = (tid & 15) * 4;
    float acc[4][4];
#pragma unroll
    for (int c = 0; c < 4; ++c) {
        int o = o_base + o_off + c;
        float bv = (o < 255) ? bd[o] : 0.f;
#pragma unroll
        for (int j = 0; j < 4; ++j) acc[c][j] = bv;
    }
    for (int cc = 0; cc < 16; ++cc) {
        for (int k = tid; k < 1024; k += 256) {
            int o = k & 63, ci = k >> 6;
            wtl[ci][o] = (o_base + o < 255) ? wd[(o_base + o) * 256 + cc * 16 + ci] : 0.f;
            ps[ci][o] = pooled[(b * 256 + cc * 16 + ci) * 1024 + px_base + o];
        }
        __syncthreads();
#pragma unroll
        for (int ci = 0; ci < 16; ++ci) {
            float4 wv = *(const float4*)&wtl[ci][o_off];
            float4 sv = *(const float4*)&ps[ci][px_off];
            acc[0][0] += wv.x * sv.x; acc[0][1] += wv.x * sv.y;
            acc[0][2] += wv.x * sv.z; acc[0][3] += wv.x * sv.w;
            acc[1][0] += wv.y * sv.x; acc[1][1] += wv.y * sv.y;
            acc[1][2] += wv.y * sv.z; acc[1][3] += wv.y * sv.w;
            acc[2][0] += wv.z * sv.x; acc[2][1] += wv.z * sv.y;
            acc[2][2] += wv.z * sv.z; acc[2][3] += wv.z * sv.w;
            acc[3][0] += wv.w * sv.x; acc[3][1] += wv.w * sv.y;
            acc[3][2] += wv.w * sv.z; acc[3][3] += wv.w * sv.w;
        }
        __syncthreads();
    }
#pragma unroll
    for (int c = 0; c < 4; ++c) {
        int o = o_base + o_off + c;
        if (o < 255)
            *(float4*)&out[(b * 255 + o) * 1024 + px_base + px_off] =
                make_float4(acc[c][0], acc[c][1], acc[c][2], acc[c][3]);
    }
}

extern "C" void kernel_launch(void* const* d_in, const int* in_sizes, int n_in,
                              void* d_out, int out_size, void* d_ws, size_t ws_size,
                              hipStream_t stream) {
    const float* x  = (const float*)d_in[0];
    const float* w1 = (const float*)d_in[1];
    const float* b1 = (const float*)d_in[2];
    const float* w2 = (const float*)d_in[3];
    const float* b2 = (const float*)d_in[4];
    const float* w3 = (const float*)d_in[5];
    const float* b3 = (const float*)d_in[6];
    const float* wd = (const float*)d_in[7];
    const float* bd = (const float*)d_in[8];
    float* out = (float*)d_out;

    // ws layout with aliasing (lifetimes):
    //   s1p u8 [2560][17544]   @ 256         (44,912,640)  live: conv1 -> conv_g8
    //   P3a f32 [40*256*1024]  @ 256         (41,943,040)  live: conv3 -> lif_mean3   (overlays s1p)
    //   s2p u8 [5120][4680]    @ 44,912,896  (23,961,600)  live: lif_s -> conv3
    //   pooled f32             @ 44,912,896  (4,194,304)   live: lif_mean3 -> det     (overlays s2p)
    //   c2  f32 [40*128*4096]  @ 68,874,496  (83,886,080)  live: conv_g8 -> lif_s
    //   P3b f32                @ 68,874,496  (41,943,040)  live: conv3 -> lif_mean3   (overlays c2)
    //   P3c f32                @ 110,817,536 (41,943,040)  live: conv3 -> lif_mean3   (overlays c2)
    //   wt2 f32 [576][128]     @ 152,760,576 (294,912)
    //   wt3 f32 [1152][256]    @ 153,055,488 (1,179,648)   end 154,235,136
    uint8_t* wsb = (uint8_t*)d_ws;
    uint8_t* s1p    = wsb + 256;
    float*   p3a    = (float*)(wsb + 256);
    uint8_t* s2p    = wsb + 44912896u;
    float*   pooled = (float*)(wsb + 44912896u);
    float*   c2     = (float*)(wsb + 68874496u);
    float*   p3b    = (float*)(wsb + 68874496u);
    float*   p3c    = (float*)(wsb + 110817536u);
    float*   wt2    = (float*)(wsb + 152760576u);
    float*   wt3    = (float*)(wsb + 153055488u);

    float alpha, beta;
    { uint32_t ab = 0x3F7383C6u; memcpy(&alpha, &ab, 4); }  // e^-0.05f
    { uint32_t bb = 0x3F519857u; memcpy(&beta,  &bb, 4); }  // e^-0.2f

    zpad<34, 129><<<2560, 256, 0, stream>>>((uint32_t*)s1p);
    zpad<18, 65><<<5120, 256, 0, stream>>>((uint32_t*)s2p);
    wtrans<<<288, 256, 0, stream>>>(w2, wt2, 576, 128);
    wtrans<<<1152, 256, 0, stream>>>(w3, wt3, 1152, 256);
    conv1_lif<<<dim3(16, 128, 4), 256, 0, stream>>>(x, w1, b1, s1p, alpha, beta);
    // L2 conv (R12): 64->128, 128->64. 8co x 4px; grid (4,16,40)=2560 blocks
    conv_g8<64, 128, 64, 16, 17544, 136, 42, 2>
        <<<dim3(4, 16, 40), 256, 0, stream>>>(s1p, wt2, c2);
    lif_s<128, 4096, 64, 72, 4680><<<dim3(4, 128, 4), 256, 0, stream>>>(c2, b2, s2p, alpha, beta);
    // L3 conv: 3 chains x 40 frames; 16co x 4px; grid (1,16,120)=1920 blocks
    conv3_chains<<<dim3(1, 16, 120), 256, 0, stream>>>(s2p, wt3, p3a, p3b, p3c);
    lif_mean3<<<dim3(1, 256, 4), 256, 0, stream>>>(p3a, p3b, p3c, b3, pooled, alpha, beta);
    det_conv<<<dim3(16, 4, 4), 256, 0, stream>>>(pooled, wd, bd, out);
}